// Round 15
// baseline (260.024 us; speedup 1.0000x reference)
//
#include <hip/hip_runtime.h>
#include <hip/hip_bf16.h>

#define DIM 512
#define NHEAD 8
#define HD 64
#define SEQ 2048
#define BATCH 4
#define NROWS (BATCH * SEQ)  // 8192

typedef __bf16 bf16;
typedef __bf16 bf16x8 __attribute__((ext_vector_type(8)));
typedef __bf16 bf16x4 __attribute__((ext_vector_type(4)));
typedef float f32x4 __attribute__((ext_vector_type(4)));
typedef unsigned short us8 __attribute__((ext_vector_type(8)));
typedef unsigned int u32x4 __attribute__((ext_vector_type(4)));
typedef unsigned int u32x2 __attribute__((ext_vector_type(2)));

__device__ __forceinline__ f32x4 mfma16(bf16x8 a, bf16x8 b, f32x4 c) {
  return __builtin_amdgcn_mfma_f32_16x16x32_bf16(a, b, c, 0, 0, 0);
}

// async global->LDS, 16B per lane; LDS dest = wave-uniform base + lane*16
__device__ __forceinline__ void gload16(const bf16* g, bf16* l) {
  __builtin_amdgcn_global_load_lds((const __attribute__((address_space(1))) void*)g,
                                   (__attribute__((address_space(3))) void*)l, 16, 0, 0);
}

// ---------- A f32 -> bf16, permuted into attention fragment order ----------
// geometry for 4-wave attn blocks: row = it*128 + wave*32 + mf*16 + ql, it in 0..15
__global__ __launch_bounds__(256, 4) void permute_a(const float* __restrict__ A,
                                                    bf16* __restrict__ out) {
  const int jt = blockIdx.x, it = blockIdx.y, b = blockIdx.z;  // (16,16,4)
  const int t = threadIdx.x;
  const int ql = t & 15, kg = (t >> 4) & 3, wave = t >> 6;  // wave 0..3
#pragma unroll
  for (int mf = 0; mf < 2; mf++) {
    const int row = it * 128 + wave * 32 + mf * 16 + ql;
    const float* arow = A + ((size_t)b * SEQ + row) * SEQ + jt * 128 + kg * 4;
    bf16* obase = out + ((((size_t)((b * 16 + it) * 16 + jt) * 2 + mf) * 4) * 256 + t) * 8;
#pragma unroll
    for (int c = 0; c < 4; c++) {
      float4 lo = *(const float4*)(arow + (2 * c) * 16);
      float4 hi = *(const float4*)(arow + (2 * c) * 16 + 16);
      bf16x8 o;
      o[0] = (bf16)lo.x; o[1] = (bf16)lo.y; o[2] = (bf16)lo.z; o[3] = (bf16)lo.w;
      o[4] = (bf16)hi.x; o[5] = (bf16)hi.y; o[6] = (bf16)hi.z; o[7] = (bf16)hi.w;
      *(bf16x8*)(obase + (size_t)c * 256 * 8) = o;
    }
  }
}

// ---------- fused weight transpose+convert: all 4 weights in one launch ----------
__global__ __launch_bounds__(256, 8) void convert_all(
    const float* __restrict__ s0, const float* __restrict__ s1, const float* __restrict__ s2,
    const float* __restrict__ s3, bf16* __restrict__ d0, bf16* __restrict__ d1,
    bf16* __restrict__ d2, bf16* __restrict__ d3) {
  __shared__ float tile[32][33];
  int id = blockIdx.x;
  const float* src;
  bf16* dst;
  int R, C, tid;
  if (id < 768) {
    src = s0; dst = d0; R = 512; C = 1536; tid = id;
  } else if (id < 1024) {
    src = s1; dst = d1; R = 512; C = 512; tid = id - 768;
  } else if (id < 2048) {
    src = s2; dst = d2; R = 512; C = 2048; tid = id - 1024;
  } else {
    src = s3; dst = d3; R = 2048; C = 512; tid = id - 2048;
  }
  const int cw = C / 32;
  const int bx = tid % cw, by = tid / cw;
  const int tx = threadIdx.x & 31, ty = threadIdx.x >> 5;  // 32 x 8
#pragma unroll
  for (int i = 0; i < 32; i += 8)
    tile[ty + i][tx] = src[(size_t)(by * 32 + ty + i) * C + bx * 32 + tx];
  __syncthreads();
#pragma unroll
  for (int i = 0; i < 32; i += 8)
    dst[(size_t)(bx * 32 + ty + i) * R + by * 32 + tx] = (bf16)tile[tx][ty + i];
}

// ---------- layernorm over 512 cols, one wave per row, bf16 out ----------
__global__ __launch_bounds__(256, 8) void ln_kernel(const float* __restrict__ in,
                                                    const float* __restrict__ g,
                                                    const float* __restrict__ b,
                                                    bf16* __restrict__ out) {
  int row = blockIdx.x * 4 + (threadIdx.x >> 6);
  int lane = threadIdx.x & 63;
  const float4* p = (const float4*)(in + (size_t)row * DIM);
  float4 v0 = p[lane];
  float4 v1 = p[lane + 64];
  float s = v0.x + v0.y + v0.z + v0.w + v1.x + v1.y + v1.z + v1.w;
#pragma unroll
  for (int m = 1; m < 64; m <<= 1) s += __shfl_xor(s, m);
  float mean = s * (1.0f / DIM);
  float d0 = v0.x - mean, d1 = v0.y - mean, d2 = v0.z - mean, d3 = v0.w - mean;
  float d4 = v1.x - mean, d5 = v1.y - mean, d6 = v1.z - mean, d7 = v1.w - mean;
  float q = d0 * d0 + d1 * d1 + d2 * d2 + d3 * d3 + d4 * d4 + d5 * d5 + d6 * d6 + d7 * d7;
#pragma unroll
  for (int m = 1; m < 64; m <<= 1) q += __shfl_xor(q, m);
  float rstd = rsqrtf(q * (1.0f / DIM) + 1e-5f);
  const float4* gp = (const float4*)g;
  const float4* bp = (const float4*)b;
  float4 g0 = gp[lane], g1 = gp[lane + 64];
  float4 b0 = bp[lane], b1 = bp[lane + 64];
  bf16x4 oa, ob;
  oa[0] = (bf16)(d0 * rstd * g0.x + b0.x);
  oa[1] = (bf16)(d1 * rstd * g0.y + b0.y);
  oa[2] = (bf16)(d2 * rstd * g0.z + b0.z);
  oa[3] = (bf16)(d3 * rstd * g0.w + b0.w);
  ob[0] = (bf16)(d4 * rstd * g1.x + b1.x);
  ob[1] = (bf16)(d5 * rstd * g1.y + b1.y);
  ob[2] = (bf16)(d6 * rstd * g1.z + b1.z);
  ob[3] = (bf16)(d7 * rstd * g1.w + b1.w);
  *(bf16x4*)(out + (size_t)row * DIM + lane * 4) = oa;
  *(bf16x4*)(out + (size_t)row * DIM + 256 + lane * 4) = ob;
}

// ---------- GEMM: single-buffer global_load_lds; 4 blk/CU; XCD-chunked swizzle ----------
#define GBM 128
#define GBN 128
#define GBK 64

enum { EPI_BF16 = 0, EPI_GELU = 1, EPI_RESID = 2 };

template <int EPI>
__global__ __launch_bounds__(256, 4) void gemm_bt(const bf16* __restrict__ A,
                                                  const bf16* __restrict__ Bt,
                                                  const float* __restrict__ bias,
                                                  const float* resid, void* outv,
                                                  int M, int N, int K) {
  __shared__ bf16 Al[GBM * GBK];
  __shared__ bf16 Bl[GBN * GBK];
  const int t = threadIdx.x;
  const int lane = t & 63;
  const int wave = t >> 6;
  const int wm = wave >> 1, wn = wave & 1;

  const int gx = gridDim.x;
  const int nwg = gx * gridDim.y;
  const int rawid = blockIdx.y * gx + blockIdx.x;
  const int q = nwg >> 3, r = nwg & 7;
  const int xcd = rawid & 7, pos = rawid >> 3;
  const int wgid = (xcd < r ? xcd * (q + 1) : r * (q + 1) + (xcd - r) * q) + pos;
  const int m0 = (wgid / gx) * GBM, n0 = (wgid % gx) * GBN;

  f32x4 acc[4][4] = {};

  const int srow0 = wave * 32 + (lane >> 3);
  const int scol = (lane & 7) * 8;
  const bf16* ga = A + (size_t)(m0 + srow0) * K + scol;
  const bf16* gb = Bt + (size_t)(n0 + srow0) * K + scol;
  bf16* lA = &Al[wave * 32 * GBK];
  bf16* lB = &Bl[wave * 32 * GBK];

#pragma unroll
  for (int i = 0; i < 4; i++) gload16(ga + (size_t)i * 8 * K, lA + i * 8 * GBK);
#pragma unroll
  for (int i = 0; i < 4; i++) gload16(gb + (size_t)i * 8 * K, lB + i * 8 * GBK);

  for (int k0 = 0; k0 < K; k0 += GBK) {
    __syncthreads();
#pragma unroll
    for (int kk = 0; kk < GBK; kk += 32) {
      bf16x8 af[4], bfr[4];
#pragma unroll
      for (int i = 0; i < 4; i++)
        af[i] = *(const bf16x8*)&Al[(wm * 64 + i * 16 + (lane & 15)) * GBK + kk + (lane >> 4) * 8];
#pragma unroll
      for (int j = 0; j < 4; j++)
        bfr[j] = *(const bf16x8*)&Bl[(wn * 64 + j * 16 + (lane & 15)) * GBK + kk + (lane >> 4) * 8];
#pragma unroll
      for (int i = 0; i < 4; i++)
#pragma unroll
        for (int j = 0; j < 4; j++) acc[i][j] = mfma16(af[i], bfr[j], acc[i][j]);
    }
    __syncthreads();
    if (k0 + GBK < K) {
      ga += GBK;
      gb += GBK;
#pragma unroll
      for (int i = 0; i < 4; i++) gload16(ga + (size_t)i * 8 * K, lA + i * 8 * GBK);
#pragma unroll
      for (int i = 0; i < 4; i++) gload16(gb + (size_t)i * 8 * K, lB + i * 8 * GBK);
    }
  }
  const int rbase = (lane >> 4) * 4;
  const int cl = lane & 15;
#pragma unroll
  for (int i = 0; i < 4; i++) {
#pragma unroll
    for (int j = 0; j < 4; j++) {
      int col = n0 + wn * 64 + j * 16 + cl;
      float bv = bias[col];
#pragma unroll
      for (int r2 = 0; r2 < 4; r2++) {
        int row = m0 + wm * 64 + i * 16 + rbase + r2;
        float v = acc[i][j][r2] + bv;
        size_t idx = (size_t)row * N + col;
        if constexpr (EPI == EPI_BF16) {
          ((bf16*)outv)[idx] = (bf16)v;
        } else if constexpr (EPI == EPI_GELU) {
          ((bf16*)outv)[idx] = (bf16)(0.5f * v * (1.0f + erff(v * 0.70710678118f)));
        } else {
          ((float*)outv)[idx] = resid[idx] + v;
        }
      }
    }
  }
}

// ---------- fused attention v3: 4 waves x 32 q (128 q/block), 2 blocks/CU ----------
// In-register P redistribution (no Pl LDS): S^T D-frag (j=nf*16+kg*4+r) -> PV A-frag
// (j=kf*32+kg*8+e) via 8 shfl + 4 selects per kf per mf. K/V dbuf, 1 barrier/tile.
__global__ __launch_bounds__(256, 2) void attn_kernel(const bf16* __restrict__ qkv,
                                                      const bf16* __restrict__ Aperm,
                                                      const float* __restrict__ edge_w,
                                                      const float* __restrict__ edge_scale,
                                                      bf16* __restrict__ out) {
  __shared__ bf16 Kl[2][128 * 64];  // 32 KB
  __shared__ bf16 Vt[2][64 * 128];  // 32 KB -> 64 KB total, 2 blocks/CU
  const int it = blockIdx.x;        // 0..15
  const int i0 = it * 128;
  const int h = blockIdx.y;
  const int b = blockIdx.z;
  const int t = threadIdx.x, lane = t & 63, wave = t >> 6;  // wave 0..3
  const int ql = lane & 15;
  const int kg = lane >> 4;  // 0..3
  const int q7 = ql & 7;
  const int sl0 = ql + ((lane & 16) << 1);  // ql + 32*(kg&1)
  const int sl1 = sl0 + 16;
  const bool up = (lane & 32) != 0;  // kg >= 2
  const float LOG2E = 1.44269504089f;
  const float esf = edge_scale[0] * edge_w[h] * LOG2E;

  const int rs = 3 * DIM;  // 1536
  const bf16* qbase = qkv + (size_t)b * SEQ * rs + h * HD;
  const bf16* kbase = qbase + DIM;
  const bf16* vbase = qbase + 2 * DIM;

  bf16x8 qf[2][2];
#pragma unroll
  for (int mf = 0; mf < 2; mf++)
#pragma unroll
    for (int kf = 0; kf < 2; kf++) {
      bf16x8 q0 = *(const bf16x8*)(qbase + (size_t)(i0 + wave * 32 + mf * 16 + ql) * rs +
                                   kf * 32 + kg * 8);
#pragma unroll
      for (int e = 0; e < 8; e++) q0[e] = (bf16)((float)q0[e] * (0.125f * LOG2E));
      qf[mf][kf] = q0;
    }

  bf16x8 vones;
#pragma unroll
  for (int e = 0; e < 8; e++) vones[e] = (bf16)1.0f;

  const bf16* abase = Aperm + (size_t)(b * 16 + it) * 262144 + (size_t)t * 8;

  float mreg[2] = {-1e30f, -1e30f};
  f32x4 lsum[2] = {};
  f32x4 oacc[2][4] = {};

  // staging geometry (256 threads): K row t>>1, half t&1 (64B); V d-octet t>>5, j-quad t&31
  const int srow = t >> 1, shalf = t & 1;
  const int vo = t >> 5, vjq = t & 31;

  u32x4 rk[4];
  us8 va[4];
  bf16x8 av[2][4];

  // ---- prologue: tile0 -> regs -> buf0; issue tile1; av tile0 ----
  {
    const bf16* krow = kbase + (size_t)srow * rs + shalf * 32;
#pragma unroll
    for (int i = 0; i < 4; i++) rk[i] = *(const u32x4*)(krow + i * 8);
#pragma unroll
    for (int jj = 0; jj < 4; jj++)
      va[jj] = *(const us8*)(vbase + (size_t)(4 * vjq + jj) * rs + vo * 8);
  }
  {
#pragma unroll
    for (int i = 0; i < 4; i++)
      *(u32x4*)&Kl[0][srow * 64 + (((shalf * 4 + i) ^ (srow & 7)) << 3)] = rk[i];
#pragma unroll
    for (int e = 0; e < 8; e++) {
      u32x2 w;
      w[0] = (unsigned)va[0][e] | ((unsigned)va[1][e] << 16);
      w[1] = (unsigned)va[2][e] | ((unsigned)va[3][e] << 16);
      *(u32x2*)&Vt[0][(vo * 8 + e) * 128 + (((vjq >> 1) ^ e) << 3) + ((vjq & 1) << 2)] = w;
    }
  }
  {
    const bf16* krow = kbase + (size_t)(128 + srow) * rs + shalf * 32;
#pragma unroll
    for (int i = 0; i < 4; i++) rk[i] = *(const u32x4*)(krow + i * 8);
#pragma unroll
    for (int jj = 0; jj < 4; jj++)
      va[jj] = *(const us8*)(vbase + (size_t)(128 + 4 * vjq + jj) * rs + vo * 8);
#pragma unroll
    for (int mf = 0; mf < 2; mf++)
#pragma unroll
      for (int c = 0; c < 4; c++)
        av[mf][c] = *(const bf16x8*)(abase + (size_t)(mf * 4 + c) * 2048);
  }
  __syncthreads();

  for (int jtid = 0; jtid < SEQ / 128; jtid++) {
    const int cur = jtid & 1;

    // S^T accumulator init from current tile's bias
    f32x4 st[2][8];
#pragma unroll
    for (int mf = 0; mf < 2; mf++)
#pragma unroll
      for (int c = 0; c < 4; c++)
#pragma unroll
        for (int r = 0; r < 4; r++) {
          st[mf][2 * c][r] = esf * (float)av[mf][c][r];
          st[mf][2 * c + 1][r] = esf * (float)av[mf][c][4 + r];
        }
    if (jtid + 1 < SEQ / 128) {
#pragma unroll
      for (int mf = 0; mf < 2; mf++)
#pragma unroll
        for (int c = 0; c < 4; c++)
          av[mf][c] = *(const bf16x8*)(abase + (size_t)((jtid + 1) * 8 + mf * 4 + c) * 2048);
    }

    // QK^T from Kl[cur]
    __builtin_amdgcn_s_setprio(1);
#pragma unroll
    for (int kf = 0; kf < 2; kf++)
#pragma unroll
      for (int nf = 0; nf < 8; nf++) {
        bf16x8 kfr =
            *(const bf16x8*)&Kl[cur][(nf * 16 + ql) * 64 + ((((kf << 2) + kg) ^ q7) << 3)];
        st[0][nf] = mfma16(kfr, qf[0][kf], st[0][nf]);
        st[1][nf] = mfma16(kfr, qf[1][kf], st[1][nf]);
      }
    __builtin_amdgcn_s_setprio(0);

    // write tile jtid+1 regs -> buf[cur^1]; issue tile jtid+2 loads
    if (jtid + 1 < SEQ / 128) {
#pragma unroll
      for (int i = 0; i < 4; i++)
        *(u32x4*)&Kl[cur ^ 1][srow * 64 + (((shalf * 4 + i) ^ (srow & 7)) << 3)] = rk[i];
#pragma unroll
      for (int e = 0; e < 8; e++) {
        u32x2 w;
        w[0] = (unsigned)va[0][e] | ((unsigned)va[1][e] << 16);
        w[1] = (unsigned)va[2][e] | ((unsigned)va[3][e] << 16);
        *(u32x2*)&Vt[cur ^ 1][(vo * 8 + e) * 128 + (((vjq >> 1) ^ e) << 3) + ((vjq & 1) << 2)] = w;
      }
      if (jtid + 2 < SEQ / 128) {
        const int jn = (jtid + 2) * 128;
        const bf16* krow = kbase + (size_t)(jn + srow) * rs + shalf * 32;
#pragma unroll
        for (int i = 0; i < 4; i++) rk[i] = *(const u32x4*)(krow + i * 8);
#pragma unroll
        for (int jj = 0; jj < 4; jj++)
          va[jj] = *(const us8*)(vbase + (size_t)(jn + 4 * vjq + jj) * rs + vo * 8);
      }
    }

    // online softmax per mf half; P packed to bf16 words in registers
    unsigned wlo[2][8], whi[2][8];
#pragma unroll
    for (int mf = 0; mf < 2; mf++) {
      float rmax = st[mf][0][0];
#pragma unroll
      for (int nf = 0; nf < 8; nf++)
#pragma unroll
        for (int r = 0; r < 4; r++) rmax = fmaxf(rmax, st[mf][nf][r]);
      rmax = fmaxf(rmax, __shfl_xor(rmax, 16));
      rmax = fmaxf(rmax, __shfl_xor(rmax, 32));
      if (__any(rmax > mreg[mf] + 8.0f)) {
        float mnew = fmaxf(mreg[mf], rmax);
        float corr = exp2f(mreg[mf] - mnew);
        mreg[mf] = mnew;
#pragma unroll
        for (int r = 0; r < 4; r++) {
          float c = __shfl(corr, kg * 4 + r);
          lsum[mf][r] *= c;
#pragma unroll
          for (int nd = 0; nd < 4; nd++) oacc[mf][nd][r] *= c;
        }
      }
#pragma unroll
      for (int nf = 0; nf < 8; nf++) {
        union {
          bf16x4 v;
          unsigned u[2];
        } U;
#pragma unroll
        for (int r = 0; r < 4; r++) U.v[r] = (bf16)exp2f(st[mf][nf][r] - mreg[mf]);
        wlo[mf][nf] = U.u[0];
        whi[mf][nf] = U.u[1];
      }
    }

    // O += P V : build pa via shfl redistribution, V from Vt[cur]
    __builtin_amdgcn_s_setprio(1);
#pragma unroll
    for (int kf = 0; kf < 4; kf++) {
      bf16x8 pa[2];
#pragma unroll
      for (int mf = 0; mf < 2; mf++) {
        unsigned a0 = (unsigned)__shfl((int)wlo[mf][2 * kf], sl0);
        unsigned a1 = (unsigned)__shfl((int)whi[mf][2 * kf], sl0);
        unsigned b0 = (unsigned)__shfl((int)wlo[mf][2 * kf + 1], sl0);
        unsigned b1 = (unsigned)__shfl((int)whi[mf][2 * kf + 1], sl0);
        unsigned c0 = (unsigned)__shfl((int)wlo[mf][2 * kf], sl1);
        unsigned c1 = (unsigned)__shfl((int)whi[mf][2 * kf], sl1);
        unsigned d0 = (unsigned)__shfl((int)wlo[mf][2 * kf + 1], sl1);
        unsigned d1 = (unsigned)__shfl((int)whi[mf][2 * kf + 1], sl1);
        union {
          unsigned u[4];
          bf16x8 v;
        } U;
        U.u[0] = up ? b0 : a0;
        U.u[1] = up ? b1 : a1;
        U.u[2] = up ? d0 : c0;
        U.u[3] = up ? d1 : c1;
        pa[mf] = U.v;
      }
      lsum[0] = mfma16(pa[0], vones, lsum[0]);
      lsum[1] = mfma16(pa[1], vones, lsum[1]);
#pragma unroll
      for (int nd = 0; nd < 4; nd++) {
        bf16x8 vv =
            *(const bf16x8*)&Vt[cur][(nd * 16 + ql) * 128 + ((((kf << 2) + kg) ^ q7) << 3)];
        oacc[0][nd] = mfma16(pa[0], vv, oacc[0][nd]);
        oacc[1][nd] = mfma16(pa[1], vv, oacc[1][nd]);
      }
    }
    __builtin_amdgcn_s_setprio(0);

    __syncthreads();  // buf[cur^1] writes done, buf[cur] reads done
  }

#pragma unroll
  for (int mf = 0; mf < 2; mf++)
#pragma unroll
    for (int r = 0; r < 4; r++) {
      float rinv = 1.0f / lsum[mf][r];
      int irow = i0 + wave * 32 + mf * 16 + kg * 4 + r;
      bf16* orow = out + ((size_t)b * SEQ + irow) * DIM + h * HD;
#pragma unroll
      for (int nd = 0; nd < 4; nd++) orow[nd * 16 + ql] = (bf16)(oacc[mf][nd][r] * rinv);
    }
}

// ---------- workspace layout ----------
constexpr size_t OFF_WQKV = 0;                                    // 1536x512 bf16
constexpr size_t OFF_WPROJ = OFF_WQKV + (size_t)1536 * 512 * 2;   // 512x512 bf16
constexpr size_t OFF_W1 = OFF_WPROJ + (size_t)512 * 512 * 2;      // 2048x512 bf16
constexpr size_t OFF_W2 = OFF_W1 + (size_t)2048 * 512 * 2;        // 512x2048 bf16
constexpr size_t OFF_XW = OFF_W2 + (size_t)512 * 2048 * 2;        // 8192x512 bf16 (x / y1)
constexpr size_t OFF_SHARED = OFF_XW + (size_t)NROWS * DIM * 2;   // qkv (24MB) / ffn1 (32MB)
constexpr size_t OFF_ATTNOUT = OFF_SHARED + (size_t)NROWS * 2048 * 2;  // 8192x512 bf16
constexpr size_t OFF_APERM = OFF_ATTNOUT + (size_t)NROWS * DIM * 2;    // 4x2048x2048 bf16
constexpr size_t WS_NEED = OFF_APERM + (size_t)BATCH * SEQ * SEQ * 2;  // ~90 MB

extern "C" void kernel_launch(void* const* d_in, const int* in_sizes, int n_in,
                              void* d_out, int out_size, void* d_ws, size_t ws_size,
                              hipStream_t stream) {
  const float* H = (const float*)d_in[0];
  const float* A = (const float*)d_in[1];
  const float* ln1_g = (const float*)d_in[2];
  const float* ln1_b = (const float*)d_in[3];
  const float* qkv_w = (const float*)d_in[4];
  const float* qkv_b = (const float*)d_in[5];
  const float* proj_w = (const float*)d_in[6];
  const float* proj_b = (const float*)d_in[7];
  const float* ln2_g = (const float*)d_in[8];
  const float* ln2_b = (const float*)d_in[9];
  const float* w1 = (const float*)d_in[10];
  const float* b1 = (const float*)d_in[11];
  const float* w2 = (const float*)d_in[12];
  const float* b2 = (const float*)d_in[13];
  const float* edge_w = (const float*)d_in[14];
  const float* edge_scale = (const float*)d_in[15];
  float* out = (float*)d_out;
  char* ws = (char*)d_ws;

  bf16* wqkv = (bf16*)(ws + OFF_WQKV);
  bf16* wproj = (bf16*)(ws + OFF_WPROJ);
  bf16* w1t = (bf16*)(ws + OFF_W1);
  bf16* w2t = (bf16*)(ws + OFF_W2);
  bf16* xw = (bf16*)(ws + OFF_XW);
  bf16* qkvb = (bf16*)(ws + OFF_SHARED);
  bf16* ffn1 = (bf16*)(ws + OFF_SHARED);
  bf16* attnout = (bf16*)(ws + OFF_ATTNOUT);
  bf16* aperm = (bf16*)(ws + OFF_APERM);

  // A -> bf16 permuted fragment-order blob (4-wave geometry)
  permute_a<<<dim3(16, 16, 4), 256, 0, stream>>>(A, aperm);
  // all weights -> bf16 transposed (N,K), fused single launch
  convert_all<<<3072, 256, 0, stream>>>(qkv_w, proj_w, w1, w2, wqkv, wproj, w1t, w2t);

  // x = LN1(H)
  ln_kernel<<<NROWS / 4, 256, 0, stream>>>(H, ln1_g, ln1_b, xw);
  // qkv = x @ qkv_w + qkv_b
  gemm_bt<EPI_BF16><<<dim3(1536 / GBN, NROWS / GBM), 256, 0, stream>>>(
      xw, wqkv, qkv_b, nullptr, qkvb, NROWS, 1536, 512);
  // attention (4 waves x 32 q, 128 q/block, 512 blocks = 2/CU, in-register P)
  attn_kernel<<<dim3(SEQ / 128, NHEAD, BATCH), 256, 0, stream>>>(qkvb, aperm, edge_w, edge_scale,
                                                                 attnout);
  // H2 = H + attnout @ proj_w + proj_b   (f32, into d_out)
  gemm_bt<EPI_RESID><<<dim3(512 / GBN, NROWS / GBM), 256, 0, stream>>>(
      attnout, wproj, proj_b, H, out, NROWS, 512, 512);
  // y1 = LN2(H2)
  ln_kernel<<<NROWS / 4, 256, 0, stream>>>(out, ln2_g, ln2_b, xw);
  // ffn1 = gelu(y1 @ w1 + b1)
  gemm_bt<EPI_GELU><<<dim3(2048 / GBN, NROWS / GBM), 256, 0, stream>>>(
      xw, w1t, b1, nullptr, ffn1, NROWS, 2048, 512);
  // out = H2 + ffn1 @ w2 + b2
  gemm_bt<EPI_RESID><<<dim3(512 / GBN, NROWS / GBM), 256, 0, stream>>>(
      ffn1, w2t, b2, out, out, NROWS, 512, 2048);
}

// Round 17
// 236.161 us; speedup vs baseline: 1.1010x; 1.1010x over previous
//
#include <hip/hip_runtime.h>
#include <hip/hip_bf16.h>

#define DIM 512
#define NHEAD 8
#define HD 64
#define SEQ 2048
#define BATCH 4
#define NROWS (BATCH * SEQ)  // 8192

typedef __bf16 bf16;
typedef __bf16 bf16x8 __attribute__((ext_vector_type(8)));
typedef __bf16 bf16x4 __attribute__((ext_vector_type(4)));
typedef float f32x4 __attribute__((ext_vector_type(4)));
typedef unsigned short us8 __attribute__((ext_vector_type(8)));
typedef unsigned int u32x4 __attribute__((ext_vector_type(4)));

__device__ __forceinline__ f32x4 mfma16(bf16x8 a, bf16x8 b, f32x4 c) {
  return __builtin_amdgcn_mfma_f32_16x16x32_bf16(a, b, c, 0, 0, 0);
}

// async global->LDS, 16B per lane; LDS dest = wave-uniform base + lane*16
__device__ __forceinline__ void gload16(const bf16* g, bf16* l) {
  __builtin_amdgcn_global_load_lds((const __attribute__((address_space(1))) void*)g,
                                   (__attribute__((address_space(3))) void*)l, 16, 0, 0);
}

// ---------- A f32 -> bf16, permuted into attention fragment order ----------
// 8-wave geometry: row = it*256 + wave*32 + mf*16 + ql, it in 0..7
__global__ __launch_bounds__(512, 2) void permute_a(const float* __restrict__ A,
                                                    bf16* __restrict__ out) {
  const int jt = blockIdx.x, it = blockIdx.y, b = blockIdx.z;  // (16,8,4)
  const int t = threadIdx.x;
  const int ql = t & 15, kg = (t >> 4) & 3, wave = t >> 6;
#pragma unroll
  for (int mf = 0; mf < 2; mf++) {
    const int row = it * 256 + wave * 32 + mf * 16 + ql;
    const float* arow = A + ((size_t)b * SEQ + row) * SEQ + jt * 128 + kg * 4;
    bf16* obase = out + ((((size_t)((b * 8 + it) * 16 + jt) * 2 + mf) * 4) * 512 + t) * 8;
#pragma unroll
    for (int c = 0; c < 4; c++) {
      float4 lo = *(const float4*)(arow + (2 * c) * 16);
      float4 hi = *(const float4*)(arow + (2 * c) * 16 + 16);
      bf16x8 o;
      o[0] = (bf16)lo.x; o[1] = (bf16)lo.y; o[2] = (bf16)lo.z; o[3] = (bf16)lo.w;
      o[4] = (bf16)hi.x; o[5] = (bf16)hi.y; o[6] = (bf16)hi.z; o[7] = (bf16)hi.w;
      *(bf16x8*)(obase + (size_t)c * 512 * 8) = o;
    }
  }
}

// ---------- fused weight transpose+convert: all 4 weights in one launch ----------
__global__ __launch_bounds__(256, 8) void convert_all(
    const float* __restrict__ s0, const float* __restrict__ s1, const float* __restrict__ s2,
    const float* __restrict__ s3, bf16* __restrict__ d0, bf16* __restrict__ d1,
    bf16* __restrict__ d2, bf16* __restrict__ d3) {
  __shared__ float tile[32][33];
  int id = blockIdx.x;
  const float* src;
  bf16* dst;
  int R, C, tid;
  if (id < 768) {
    src = s0; dst = d0; R = 512; C = 1536; tid = id;
  } else if (id < 1024) {
    src = s1; dst = d1; R = 512; C = 512; tid = id - 768;
  } else if (id < 2048) {
    src = s2; dst = d2; R = 512; C = 2048; tid = id - 1024;
  } else {
    src = s3; dst = d3; R = 2048; C = 512; tid = id - 2048;
  }
  const int cw = C / 32;
  const int bx = tid % cw, by = tid / cw;
  const int tx = threadIdx.x & 31, ty = threadIdx.x >> 5;  // 32 x 8
#pragma unroll
  for (int i = 0; i < 32; i += 8)
    tile[ty + i][tx] = src[(size_t)(by * 32 + ty + i) * C + bx * 32 + tx];
  __syncthreads();
#pragma unroll
  for (int i = 0; i < 32; i += 8)
    dst[(size_t)(bx * 32 + ty + i) * R + by * 32 + tx] = (bf16)tile[tx][ty + i];
}

// ---------- layernorm over 512 cols, one wave per row, bf16 out ----------
__global__ __launch_bounds__(256, 8) void ln_kernel(const float* __restrict__ in,
                                                    const float* __restrict__ g,
                                                    const float* __restrict__ b,
                                                    bf16* __restrict__ out) {
  int row = blockIdx.x * 4 + (threadIdx.x >> 6);
  int lane = threadIdx.x & 63;
  const float4* p = (const float4*)(in + (size_t)row * DIM);
  float4 v0 = p[lane];
  float4 v1 = p[lane + 64];
  float s = v0.x + v0.y + v0.z + v0.w + v1.x + v1.y + v1.z + v1.w;
#pragma unroll
  for (int m = 1; m < 64; m <<= 1) s += __shfl_xor(s, m);
  float mean = s * (1.0f / DIM);
  float d0 = v0.x - mean, d1 = v0.y - mean, d2 = v0.z - mean, d3 = v0.w - mean;
  float d4 = v1.x - mean, d5 = v1.y - mean, d6 = v1.z - mean, d7 = v1.w - mean;
  float q = d0 * d0 + d1 * d1 + d2 * d2 + d3 * d3 + d4 * d4 + d5 * d5 + d6 * d6 + d7 * d7;
#pragma unroll
  for (int m = 1; m < 64; m <<= 1) q += __shfl_xor(q, m);
  float rstd = rsqrtf(q * (1.0f / DIM) + 1e-5f);
  const float4* gp = (const float4*)g;
  const float4* bp = (const float4*)b;
  float4 g0 = gp[lane], g1 = gp[lane + 64];
  float4 b0 = bp[lane], b1 = bp[lane + 64];
  bf16x4 oa, ob;
  oa[0] = (bf16)(d0 * rstd * g0.x + b0.x);
  oa[1] = (bf16)(d1 * rstd * g0.y + b0.y);
  oa[2] = (bf16)(d2 * rstd * g0.z + b0.z);
  oa[3] = (bf16)(d3 * rstd * g0.w + b0.w);
  ob[0] = (bf16)(d4 * rstd * g1.x + b1.x);
  ob[1] = (bf16)(d5 * rstd * g1.y + b1.y);
  ob[2] = (bf16)(d6 * rstd * g1.z + b1.z);
  ob[3] = (bf16)(d7 * rstd * g1.w + b1.w);
  *(bf16x4*)(out + (size_t)row * DIM + lane * 4) = oa;
  *(bf16x4*)(out + (size_t)row * DIM + 256 + lane * 4) = ob;
}

// ---------- GEMM: single-buffer global_load_lds; 4 blk/CU; XCD-chunked swizzle ----------
#define GBM 128
#define GBN 128
#define GBK 64

enum { EPI_BF16 = 0, EPI_GELU = 1, EPI_RESID = 2 };

template <int EPI>
__global__ __launch_bounds__(256, 4) void gemm_bt(const bf16* __restrict__ A,
                                                  const bf16* __restrict__ Bt,
                                                  const float* __restrict__ bias,
                                                  const float* resid, void* outv,
                                                  int M, int N, int K) {
  __shared__ bf16 Al[GBM * GBK];
  __shared__ bf16 Bl[GBN * GBK];
  const int t = threadIdx.x;
  const int lane = t & 63;
  const int wave = t >> 6;
  const int wm = wave >> 1, wn = wave & 1;

  const int gx = gridDim.x;
  const int nwg = gx * gridDim.y;
  const int rawid = blockIdx.y * gx + blockIdx.x;
  const int q = nwg >> 3, r = nwg & 7;
  const int xcd = rawid & 7, pos = rawid >> 3;
  const int wgid = (xcd < r ? xcd * (q + 1) : r * (q + 1) + (xcd - r) * q) + pos;
  const int m0 = (wgid / gx) * GBM, n0 = (wgid % gx) * GBN;

  f32x4 acc[4][4] = {};

  const int srow0 = wave * 32 + (lane >> 3);
  const int scol = (lane & 7) * 8;
  const bf16* ga = A + (size_t)(m0 + srow0) * K + scol;
  const bf16* gb = Bt + (size_t)(n0 + srow0) * K + scol;
  bf16* lA = &Al[wave * 32 * GBK];
  bf16* lB = &Bl[wave * 32 * GBK];

#pragma unroll
  for (int i = 0; i < 4; i++) gload16(ga + (size_t)i * 8 * K, lA + i * 8 * GBK);
#pragma unroll
  for (int i = 0; i < 4; i++) gload16(gb + (size_t)i * 8 * K, lB + i * 8 * GBK);

  for (int k0 = 0; k0 < K; k0 += GBK) {
    __syncthreads();
#pragma unroll
    for (int kk = 0; kk < GBK; kk += 32) {
      bf16x8 af[4], bfr[4];
#pragma unroll
      for (int i = 0; i < 4; i++)
        af[i] = *(const bf16x8*)&Al[(wm * 64 + i * 16 + (lane & 15)) * GBK + kk + (lane >> 4) * 8];
#pragma unroll
      for (int j = 0; j < 4; j++)
        bfr[j] = *(const bf16x8*)&Bl[(wn * 64 + j * 16 + (lane & 15)) * GBK + kk + (lane >> 4) * 8];
#pragma unroll
      for (int i = 0; i < 4; i++)
#pragma unroll
        for (int j = 0; j < 4; j++) acc[i][j] = mfma16(af[i], bfr[j], acc[i][j]);
    }
    __syncthreads();
    if (k0 + GBK < K) {
      ga += GBK;
      gb += GBK;
#pragma unroll
      for (int i = 0; i < 4; i++) gload16(ga + (size_t)i * 8 * K, lA + i * 8 * GBK);
#pragma unroll
      for (int i = 0; i < 4; i++) gload16(gb + (size_t)i * 8 * K, lB + i * 8 * GBK);
    }
  }
  const int rbase = (lane >> 4) * 4;
  const int cl = lane & 15;
#pragma unroll
  for (int i = 0; i < 4; i++) {
#pragma unroll
    for (int j = 0; j < 4; j++) {
      int col = n0 + wn * 64 + j * 16 + cl;
      float bv = bias[col];
#pragma unroll
      for (int r2 = 0; r2 < 4; r2++) {
        int row = m0 + wm * 64 + i * 16 + rbase + r2;
        float v = acc[i][j][r2] + bv;
        size_t idx = (size_t)row * N + col;
        if constexpr (EPI == EPI_BF16) {
          ((bf16*)outv)[idx] = (bf16)v;
        } else if constexpr (EPI == EPI_GELU) {
          ((bf16*)outv)[idx] = (bf16)(0.5f * v * (1.0f + erff(v * 0.70710678118f)));
        } else {
          ((float*)outv)[idx] = resid[idx] + v;
        }
      }
    }
  }
}

// ---------- fused attention (R14 known-good): 8 waves x 32 q; K/V dbuf, 1 barrier/tile ----------
__global__ __launch_bounds__(512, 2) void attn_kernel(const bf16* __restrict__ qkv,
                                                      const bf16* __restrict__ Aperm,
                                                      const float* __restrict__ edge_w,
                                                      const float* __restrict__ edge_scale,
                                                      bf16* __restrict__ out) {
  __shared__ bf16 Kl[2][128 * 64];      // 32 KB
  __shared__ bf16 Vt[2][64 * 128];      // 32 KB
  __shared__ bf16 Pl[8][2][16 * 128];   // 64 KB -> 128 KB total
  const int it = blockIdx.x;
  const int i0 = it * 256;
  const int h = blockIdx.y;
  const int b = blockIdx.z;
  const int t = threadIdx.x, lane = t & 63, wave = t >> 6;
  const int ql = lane & 15;
  const int kg = lane >> 4;
  const int q7 = ql & 7;
  const float LOG2E = 1.44269504089f;
  const float esf = edge_scale[0] * edge_w[h] * LOG2E;

  const int rs = 3 * DIM;  // 1536
  const bf16* qbase = qkv + (size_t)b * SEQ * rs + h * HD;
  const bf16* kbase = qbase + DIM;
  const bf16* vbase = qbase + 2 * DIM;

  bf16x8 qf[2][2];
#pragma unroll
  for (int mf = 0; mf < 2; mf++)
#pragma unroll
    for (int kf = 0; kf < 2; kf++) {
      bf16x8 q0 = *(const bf16x8*)(qbase + (size_t)(i0 + wave * 32 + mf * 16 + ql) * rs +
                                   kf * 32 + kg * 8);
#pragma unroll
      for (int e = 0; e < 8; e++) q0[e] = (bf16)((float)q0[e] * (0.125f * LOG2E));
      qf[mf][kf] = q0;
    }

  bf16x8 vones;
#pragma unroll
  for (int e = 0; e < 8; e++) vones[e] = (bf16)1.0f;

  const bf16* abase = Aperm + ((size_t)(b * 8 + it) * 16 * 8) * 4096 + (size_t)t * 8;

  float mreg[2] = {-1e30f, -1e30f};
  f32x4 lsum[2] = {};
  f32x4 oacc[2][4] = {};

  const int srow = t >> 2, sq4 = t & 3;
  const int jp = t & 63, doct = t >> 6;

  u32x4 rk0, rk1;
  us8 va0, va1;
  bf16x8 av[2][4];
  // ---- prologue: load tile0, write buf0, issue tile1, load av tile0 ----
  {
    const bf16* krow = kbase + (size_t)srow * rs + sq4 * 16;
    rk0 = *(const u32x4*)(krow);
    rk1 = *(const u32x4*)(krow + 8);
    const bf16* vr0 = vbase + (size_t)(2 * jp) * rs + doct * 8;
    va0 = *(const us8*)(vr0);
    va1 = *(const us8*)(vr0 + rs);
  }
  {
    *(u32x4*)&Kl[0][srow * 64 + (((2 * sq4 + 0) ^ (srow & 7)) << 3)] = rk0;
    *(u32x4*)&Kl[0][srow * 64 + (((2 * sq4 + 1) ^ (srow & 7)) << 3)] = rk1;
#pragma unroll
    for (int jj = 0; jj < 8; jj++) {
      unsigned w0 = (unsigned)va0[jj] | ((unsigned)va1[jj] << 16);
      *(unsigned*)&Vt[0][(doct * 8 + jj) * 128 + (((jp >> 2) ^ jj) << 3) + 2 * (jp & 3)] = w0;
    }
  }
  {
    const bf16* krow = kbase + (size_t)(128 + srow) * rs + sq4 * 16;
    rk0 = *(const u32x4*)(krow);
    rk1 = *(const u32x4*)(krow + 8);
    const bf16* vr0 = vbase + (size_t)(128 + 2 * jp) * rs + doct * 8;
    va0 = *(const us8*)(vr0);
    va1 = *(const us8*)(vr0 + rs);
#pragma unroll
    for (int mf = 0; mf < 2; mf++)
#pragma unroll
      for (int c = 0; c < 4; c++)
        av[mf][c] = *(const bf16x8*)(abase + (size_t)(mf * 4 + c) * 4096);
  }
  __syncthreads();  // buf0 visible to all waves

  for (int jtid = 0; jtid < SEQ / 128; jtid++) {
    const int cur = jtid & 1;

    // S^T accumulator init from current tile's bias (av = tile jtid)
    f32x4 st[2][8];
#pragma unroll
    for (int mf = 0; mf < 2; mf++)
#pragma unroll
      for (int c = 0; c < 4; c++)
#pragma unroll
        for (int r = 0; r < 4; r++) {
          st[mf][2 * c][r] = esf * (float)av[mf][c][r];
          st[mf][2 * c + 1][r] = esf * (float)av[mf][c][4 + r];
        }
    // issue av loads for tile jtid+1
    if (jtid + 1 < SEQ / 128) {
#pragma unroll
      for (int mf = 0; mf < 2; mf++)
#pragma unroll
        for (int c = 0; c < 4; c++)
          av[mf][c] = *(const bf16x8*)(abase + (size_t)((jtid + 1) * 8 + mf * 4 + c) * 4096);
    }

    // QK^T from Kl[cur]
    __builtin_amdgcn_s_setprio(1);
#pragma unroll
    for (int kf = 0; kf < 2; kf++)
#pragma unroll
      for (int nf = 0; nf < 8; nf++) {
        bf16x8 kfr =
            *(const bf16x8*)&Kl[cur][(nf * 16 + ql) * 64 + ((((kf << 2) + kg) ^ q7) << 3)];
        st[0][nf] = mfma16(kfr, qf[0][kf], st[0][nf]);
        st[1][nf] = mfma16(kfr, qf[1][kf], st[1][nf]);
      }
    __builtin_amdgcn_s_setprio(0);

    // write tile jtid+1 (regs) -> buf[cur^1]; its last readers finished at barrier jtid-1
    if (jtid + 1 < SEQ / 128) {
      *(u32x4*)&Kl[cur ^ 1][srow * 64 + (((2 * sq4 + 0) ^ (srow & 7)) << 3)] = rk0;
      *(u32x4*)&Kl[cur ^ 1][srow * 64 + (((2 * sq4 + 1) ^ (srow & 7)) << 3)] = rk1;
#pragma unroll
      for (int jj = 0; jj < 8; jj++) {
        unsigned w0 = (unsigned)va0[jj] | ((unsigned)va1[jj] << 16);
        *(unsigned*)&Vt[cur ^ 1][(doct * 8 + jj) * 128 + (((jp >> 2) ^ jj) << 3) + 2 * (jp & 3)] =
            w0;
      }
      // issue tile jtid+2 global loads
      if (jtid + 2 < SEQ / 128) {
        const int jn = (jtid + 2) * 128;
        const bf16* krow = kbase + (size_t)(jn + srow) * rs + sq4 * 16;
        rk0 = *(const u32x4*)(krow);
        rk1 = *(const u32x4*)(krow + 8);
        const bf16* vr0 = vbase + (size_t)(jn + 2 * jp) * rs + doct * 8;
        va0 = *(const us8*)(vr0);
        va1 = *(const us8*)(vr0 + rs);
      }
    }

    // online softmax per mf half, defer-max THR=8 (log2 domain)
#pragma unroll
    for (int mf = 0; mf < 2; mf++) {
      float rmax = st[mf][0][0];
#pragma unroll
      for (int nf = 0; nf < 8; nf++)
#pragma unroll
        for (int r = 0; r < 4; r++) rmax = fmaxf(rmax, st[mf][nf][r]);
      rmax = fmaxf(rmax, __shfl_xor(rmax, 16));
      rmax = fmaxf(rmax, __shfl_xor(rmax, 32));
      if (__any(rmax > mreg[mf] + 8.0f)) {
        float mnew = fmaxf(mreg[mf], rmax);
        float corr = exp2f(mreg[mf] - mnew);
        mreg[mf] = mnew;
#pragma unroll
        for (int r = 0; r < 4; r++) {
          float c = __shfl(corr, kg * 4 + r);
          lsum[mf][r] *= c;
#pragma unroll
          for (int nd = 0; nd < 4; nd++) oacc[mf][nd][r] *= c;
        }
      }
#pragma unroll
      for (int nf = 0; nf < 8; nf++) {
        bf16x4 pk;
#pragma unroll
        for (int r = 0; r < 4; r++) pk[r] = (bf16)exp2f(st[mf][nf][r] - mreg[mf]);
        *(bf16x4*)&Pl[wave][mf][ql * 128 + (((2 * nf + (kg >> 1)) ^ q7) << 3) + (kg & 1) * 4] = pk;
      }
    }

    // O += P V from Vt[cur]
    __builtin_amdgcn_s_setprio(1);
#pragma unroll
    for (int kf = 0; kf < 4; kf++) {
      bf16x8 pa0 = *(const bf16x8*)&Pl[wave][0][ql * 128 + ((((kf << 2) + kg) ^ q7) << 3)];
      bf16x8 pa1 = *(const bf16x8*)&Pl[wave][1][ql * 128 + ((((kf << 2) + kg) ^ q7) << 3)];
      lsum[0] = mfma16(pa0, vones, lsum[0]);
      lsum[1] = mfma16(pa1, vones, lsum[1]);
#pragma unroll
      for (int nd = 0; nd < 4; nd++) {
        bf16x8 vv =
            *(const bf16x8*)&Vt[cur][(nd * 16 + ql) * 128 + ((((kf << 2) + kg) ^ q7) << 3)];
        oacc[0][nd] = mfma16(pa0, vv, oacc[0][nd]);
        oacc[1][nd] = mfma16(pa1, vv, oacc[1][nd]);
      }
    }
    __builtin_amdgcn_s_setprio(0);

    __syncthreads();  // one barrier per tile
  }

#pragma unroll
  for (int mf = 0; mf < 2; mf++)
#pragma unroll
    for (int r = 0; r < 4; r++) {
      float rinv = 1.0f / lsum[mf][r];
      int irow = i0 + wave * 32 + mf * 16 + kg * 4 + r;
      bf16* orow = out + ((size_t)b * SEQ + irow) * DIM + h * HD;
#pragma unroll
      for (int nd = 0; nd < 4; nd++) orow[nd * 16 + ql] = (bf16)(oacc[mf][nd][r] * rinv);
    }
}

// ---------- workspace layout ----------
constexpr size_t OFF_WQKV = 0;                                    // 1536x512 bf16
constexpr size_t OFF_WPROJ = OFF_WQKV + (size_t)1536 * 512 * 2;   // 512x512 bf16
constexpr size_t OFF_W1 = OFF_WPROJ + (size_t)512 * 512 * 2;      // 2048x512 bf16
constexpr size_t OFF_W2 = OFF_W1 + (size_t)2048 * 512 * 2;        // 512x2048 bf16
constexpr size_t OFF_XW = OFF_W2 + (size_t)512 * 2048 * 2;        // 8192x512 bf16 (x / y1)
constexpr size_t OFF_SHARED = OFF_XW + (size_t)NROWS * DIM * 2;   // qkv (24MB) / ffn1 (32MB)
constexpr size_t OFF_ATTNOUT = OFF_SHARED + (size_t)NROWS * 2048 * 2;  // 8192x512 bf16
constexpr size_t OFF_APERM = OFF_ATTNOUT + (size_t)NROWS * DIM * 2;    // 4x2048x2048 bf16
constexpr size_t WS_NEED = OFF_APERM + (size_t)BATCH * SEQ * SEQ * 2;  // ~90 MB

extern "C" void kernel_launch(void* const* d_in, const int* in_sizes, int n_in,
                              void* d_out, int out_size, void* d_ws, size_t ws_size,
                              hipStream_t stream) {
  const float* H = (const float*)d_in[0];
  const float* A = (const float*)d_in[1];
  const float* ln1_g = (const float*)d_in[2];
  const float* ln1_b = (const float*)d_in[3];
  const float* qkv_w = (const float*)d_in[4];
  const float* qkv_b = (const float*)d_in[5];
  const float* proj_w = (const float*)d_in[6];
  const float* proj_b = (const float*)d_in[7];
  const float* ln2_g = (const float*)d_in[8];
  const float* ln2_b = (const float*)d_in[9];
  const float* w1 = (const float*)d_in[10];
  const float* b1 = (const float*)d_in[11];
  const float* w2 = (const float*)d_in[12];
  const float* b2 = (const float*)d_in[13];
  const float* edge_w = (const float*)d_in[14];
  const float* edge_scale = (const float*)d_in[15];
  float* out = (float*)d_out;
  char* ws = (char*)d_ws;

  bf16* wqkv = (bf16*)(ws + OFF_WQKV);
  bf16* wproj = (bf16*)(ws + OFF_WPROJ);
  bf16* w1t = (bf16*)(ws + OFF_W1);
  bf16* w2t = (bf16*)(ws + OFF_W2);
  bf16* xw = (bf16*)(ws + OFF_XW);
  bf16* qkvb = (bf16*)(ws + OFF_SHARED);
  bf16* ffn1 = (bf16*)(ws + OFF_SHARED);
  bf16* attnout = (bf16*)(ws + OFF_ATTNOUT);
  bf16* aperm = (bf16*)(ws + OFF_APERM);

  // A -> bf16 permuted fragment-order blob (8-wave geometry)
  permute_a<<<dim3(16, 8, 4), 512, 0, stream>>>(A, aperm);
  // all weights -> bf16 transposed (N,K), fused single launch
  convert_all<<<3072, 256, 0, stream>>>(qkv_w, proj_w, w1, w2, wqkv, wproj, w1t, w2t);

  // x = LN1(H)
  ln_kernel<<<NROWS / 4, 256, 0, stream>>>(H, ln1_g, ln1_b, xw);
  // qkv = x @ qkv_w + qkv_b
  gemm_bt<EPI_BF16><<<dim3(1536 / GBN, NROWS / GBM), 256, 0, stream>>>(
      xw, wqkv, qkv_b, nullptr, qkvb, NROWS, 1536, 512);
  // attention (8 waves x 32 q-rows, dbuf K/V, 1 barrier/tile)
  attn_kernel<<<dim3(SEQ / 256, NHEAD, BATCH), 512, 0, stream>>>(qkvb, aperm, edge_w, edge_scale,
                                                                 attnout);
  // H2 = H + attnout @ proj_w + proj_b   (f32, into d_out)
  gemm_bt<EPI_RESID><<<dim3(512 / GBN, NROWS / GBM), 256, 0, stream>>>(
      attnout, wproj, proj_b, H, out, NROWS, 512, 512);
  // y1 = LN2(H2)
  ln_kernel<<<NROWS / 4, 256, 0, stream>>>(out, ln2_g, ln2_b, xw);
  // ffn1 = gelu(y1 @ w1 + b1)
  gemm_bt<EPI_GELU><<<dim3(2048 / GBN, NROWS / GBM), 256, 0, stream>>>(
      xw, w1t, b1, nullptr, ffn1, NROWS, 2048, 512);
  // out = H2 + ffn1 @ w2 + b2
  gemm_bt<EPI_RESID><<<dim3(512 / GBN, NROWS / GBM), 256, 0, stream>>>(
      ffn1, w2t, b2, out, out, NROWS, 512, 2048);
}

// Round 18
// 210.527 us; speedup vs baseline: 1.2351x; 1.1218x over previous
//
#include <hip/hip_runtime.h>
#include <hip/hip_bf16.h>

#define DIM 512
#define NHEAD 8
#define HD 64
#define SEQ 2048
#define BATCH 4
#define NROWS (BATCH * SEQ)  // 8192

typedef __bf16 bf16;
typedef __bf16 bf16x8 __attribute__((ext_vector_type(8)));
typedef __bf16 bf16x4 __attribute__((ext_vector_type(4)));
typedef float f32x4 __attribute__((ext_vector_type(4)));
typedef unsigned short us8 __attribute__((ext_vector_type(8)));
typedef unsigned int u32x4 __attribute__((ext_vector_type(4)));

__device__ __forceinline__ f32x4 mfma16(bf16x8 a, bf16x8 b, f32x4 c) {
  return __builtin_amdgcn_mfma_f32_16x16x32_bf16(a, b, c, 0, 0, 0);
}

// async global->LDS, 16B per lane; LDS dest = wave-uniform base + lane*16
__device__ __forceinline__ void gload16(const bf16* g, bf16* l) {
  __builtin_amdgcn_global_load_lds((const __attribute__((address_space(1))) void*)g,
                                   (__attribute__((address_space(3))) void*)l, 16, 0, 0);
}

// ---------- A f32 -> bf16, permuted into attention fragment order ----------
// 8-wave geometry: row = it*256 + wave*32 + mf*16 + ql, it in 0..7
__global__ __launch_bounds__(512, 2) void permute_a(const float* __restrict__ A,
                                                    bf16* __restrict__ out) {
  const int jt = blockIdx.x, it = blockIdx.y, b = blockIdx.z;  // (16,8,4)
  const int t = threadIdx.x;
  const int ql = t & 15, kg = (t >> 4) & 3, wave = t >> 6;
#pragma unroll
  for (int mf = 0; mf < 2; mf++) {
    const int row = it * 256 + wave * 32 + mf * 16 + ql;
    const float* arow = A + ((size_t)b * SEQ + row) * SEQ + jt * 128 + kg * 4;
    bf16* obase = out + ((((size_t)((b * 8 + it) * 16 + jt) * 2 + mf) * 4) * 512 + t) * 8;
#pragma unroll
    for (int c = 0; c < 4; c++) {
      float4 lo = *(const float4*)(arow + (2 * c) * 16);
      float4 hi = *(const float4*)(arow + (2 * c) * 16 + 16);
      bf16x8 o;
      o[0] = (bf16)lo.x; o[1] = (bf16)lo.y; o[2] = (bf16)lo.z; o[3] = (bf16)lo.w;
      o[4] = (bf16)hi.x; o[5] = (bf16)hi.y; o[6] = (bf16)hi.z; o[7] = (bf16)hi.w;
      *(bf16x8*)(obase + (size_t)c * 512 * 8) = o;
    }
  }
}

// ---------- fused weight transpose+convert: all 4 weights in one launch ----------
__global__ __launch_bounds__(256, 8) void convert_all(
    const float* __restrict__ s0, const float* __restrict__ s1, const float* __restrict__ s2,
    const float* __restrict__ s3, bf16* __restrict__ d0, bf16* __restrict__ d1,
    bf16* __restrict__ d2, bf16* __restrict__ d3) {
  __shared__ float tile[32][33];
  int id = blockIdx.x;
  const float* src;
  bf16* dst;
  int R, C, tid;
  if (id < 768) {
    src = s0; dst = d0; R = 512; C = 1536; tid = id;
  } else if (id < 1024) {
    src = s1; dst = d1; R = 512; C = 512; tid = id - 768;
  } else if (id < 2048) {
    src = s2; dst = d2; R = 512; C = 2048; tid = id - 1024;
  } else {
    src = s3; dst = d3; R = 2048; C = 512; tid = id - 2048;
  }
  const int cw = C / 32;
  const int bx = tid % cw, by = tid / cw;
  const int tx = threadIdx.x & 31, ty = threadIdx.x >> 5;  // 32 x 8
#pragma unroll
  for (int i = 0; i < 32; i += 8)
    tile[ty + i][tx] = src[(size_t)(by * 32 + ty + i) * C + bx * 32 + tx];
  __syncthreads();
#pragma unroll
  for (int i = 0; i < 32; i += 8)
    dst[(size_t)(bx * 32 + ty + i) * R + by * 32 + tx] = (bf16)tile[tx][ty + i];
}

// ---------- layernorm over 512 cols, one wave per row, bf16 out ----------
__global__ __launch_bounds__(256, 8) void ln_kernel(const float* __restrict__ in,
                                                    const float* __restrict__ g,
                                                    const float* __restrict__ b,
                                                    bf16* __restrict__ out) {
  int row = blockIdx.x * 4 + (threadIdx.x >> 6);
  int lane = threadIdx.x & 63;
  const float4* p = (const float4*)(in + (size_t)row * DIM);
  float4 v0 = p[lane];
  float4 v1 = p[lane + 64];
  float s = v0.x + v0.y + v0.z + v0.w + v1.x + v1.y + v1.z + v1.w;
#pragma unroll
  for (int m = 1; m < 64; m <<= 1) s += __shfl_xor(s, m);
  float mean = s * (1.0f / DIM);
  float d0 = v0.x - mean, d1 = v0.y - mean, d2 = v0.z - mean, d3 = v0.w - mean;
  float d4 = v1.x - mean, d5 = v1.y - mean, d6 = v1.z - mean, d7 = v1.w - mean;
  float q = d0 * d0 + d1 * d1 + d2 * d2 + d3 * d3 + d4 * d4 + d5 * d5 + d6 * d6 + d7 * d7;
#pragma unroll
  for (int m = 1; m < 64; m <<= 1) q += __shfl_xor(q, m);
  float rstd = rsqrtf(q * (1.0f / DIM) + 1e-5f);
  const float4* gp = (const float4*)g;
  const float4* bp = (const float4*)b;
  float4 g0 = gp[lane], g1 = gp[lane + 64];
  float4 b0 = bp[lane], b1 = bp[lane + 64];
  bf16x4 oa, ob;
  oa[0] = (bf16)(d0 * rstd * g0.x + b0.x);
  oa[1] = (bf16)(d1 * rstd * g0.y + b0.y);
  oa[2] = (bf16)(d2 * rstd * g0.z + b0.z);
  oa[3] = (bf16)(d3 * rstd * g0.w + b0.w);
  ob[0] = (bf16)(d4 * rstd * g1.x + b1.x);
  ob[1] = (bf16)(d5 * rstd * g1.y + b1.y);
  ob[2] = (bf16)(d6 * rstd * g1.z + b1.z);
  ob[3] = (bf16)(d7 * rstd * g1.w + b1.w);
  *(bf16x4*)(out + (size_t)row * DIM + lane * 4) = oa;
  *(bf16x4*)(out + (size_t)row * DIM + 256 + lane * 4) = ob;
}

// ---------- GEMM: tiled (BM x BN), single-buffer global_load_lds, XCD swizzle ----------
#define GBK 64

enum { EPI_BF16 = 0, EPI_GELU = 1, EPI_RESID = 2 };

// 4 waves in 2x2 grid; wave tile = (FM*16) x (FN*16); BM = 2*FM*16, BN = 2*FN*16.
template <int EPI, int FM, int FN>
__global__ __launch_bounds__(256, 4) void gemm_bt(const bf16* __restrict__ A,
                                                  const bf16* __restrict__ Bt,
                                                  const float* __restrict__ bias,
                                                  const float* resid, void* outv,
                                                  int M, int N, int K) {
  constexpr int BM = 2 * FM * 16, BN = 2 * FN * 16;
  constexpr int RA = BM / 4, NA = RA / 8;  // rows per wave, gload instrs per wave (A)
  constexpr int RB = BN / 4, NB = RB / 8;
  __shared__ bf16 Al[BM * GBK];
  __shared__ bf16 Bl[BN * GBK];
  const int t = threadIdx.x;
  const int lane = t & 63;
  const int wave = t >> 6;
  const int wm = wave >> 1, wn = wave & 1;

  // XCD-chunked bijective block swizzle (m204)
  const int gx = gridDim.x;
  const int nwg = gx * gridDim.y;
  const int rawid = blockIdx.y * gx + blockIdx.x;
  const int q = nwg >> 3, r = nwg & 7;
  const int xcd = rawid & 7, pos = rawid >> 3;
  const int wgid = (xcd < r ? xcd * (q + 1) : r * (q + 1) + (xcd - r) * q) + pos;
  const int m0 = (wgid / gx) * BM, n0 = (wgid % gx) * BN;

  f32x4 acc[FM][FN] = {};

  const int arow0 = wave * RA + (lane >> 3);
  const int brow0 = wave * RB + (lane >> 3);
  const int scol = (lane & 7) * 8;
  const bf16* ga = A + (size_t)(m0 + arow0) * K + scol;
  const bf16* gb = Bt + (size_t)(n0 + brow0) * K + scol;
  bf16* lA = &Al[wave * RA * GBK];
  bf16* lB = &Bl[wave * RB * GBK];

#pragma unroll
  for (int i = 0; i < NA; i++) gload16(ga + (size_t)i * 8 * K, lA + i * 8 * GBK);
#pragma unroll
  for (int i = 0; i < NB; i++) gload16(gb + (size_t)i * 8 * K, lB + i * 8 * GBK);

  for (int k0 = 0; k0 < K; k0 += GBK) {
    __syncthreads();  // drains vmcnt -> tile resident
#pragma unroll
    for (int kk = 0; kk < GBK; kk += 32) {
      bf16x8 af[FM], bfr[FN];
#pragma unroll
      for (int i = 0; i < FM; i++)
        af[i] =
            *(const bf16x8*)&Al[(wm * FM * 16 + i * 16 + (lane & 15)) * GBK + kk + (lane >> 4) * 8];
#pragma unroll
      for (int j = 0; j < FN; j++)
        bfr[j] =
            *(const bf16x8*)&Bl[(wn * FN * 16 + j * 16 + (lane & 15)) * GBK + kk + (lane >> 4) * 8];
#pragma unroll
      for (int i = 0; i < FM; i++)
#pragma unroll
        for (int j = 0; j < FN; j++) acc[i][j] = mfma16(af[i], bfr[j], acc[i][j]);
    }
    __syncthreads();  // all reads done; safe to overwrite
    if (k0 + GBK < K) {
      ga += GBK;
      gb += GBK;
#pragma unroll
      for (int i = 0; i < NA; i++) gload16(ga + (size_t)i * 8 * K, lA + i * 8 * GBK);
#pragma unroll
      for (int i = 0; i < NB; i++) gload16(gb + (size_t)i * 8 * K, lB + i * 8 * GBK);
    }
  }
  const int rbase = (lane >> 4) * 4;
  const int cl = lane & 15;
#pragma unroll
  for (int i = 0; i < FM; i++) {
#pragma unroll
    for (int j = 0; j < FN; j++) {
      int col = n0 + wn * FN * 16 + j * 16 + cl;
      float bv = bias[col];
#pragma unroll
      for (int r2 = 0; r2 < 4; r2++) {
        int row = m0 + wm * FM * 16 + i * 16 + rbase + r2;
        float v = acc[i][j][r2] + bv;
        size_t idx = (size_t)row * N + col;
        if constexpr (EPI == EPI_BF16) {
          ((bf16*)outv)[idx] = (bf16)v;
        } else if constexpr (EPI == EPI_GELU) {
          ((bf16*)outv)[idx] = (bf16)(0.5f * v * (1.0f + erff(v * 0.70710678118f)));
        } else {
          ((float*)outv)[idx] = resid[idx] + v;
        }
      }
    }
  }
}

// ---------- fused attention (R14 known-good): 8 waves x 32 q; K/V dbuf, 1 barrier/tile ----------
__global__ __launch_bounds__(512, 2) void attn_kernel(const bf16* __restrict__ qkv,
                                                      const bf16* __restrict__ Aperm,
                                                      const float* __restrict__ edge_w,
                                                      const float* __restrict__ edge_scale,
                                                      bf16* __restrict__ out) {
  __shared__ bf16 Kl[2][128 * 64];      // 32 KB
  __shared__ bf16 Vt[2][64 * 128];      // 32 KB
  __shared__ bf16 Pl[8][2][16 * 128];   // 64 KB -> 128 KB total
  const int it = blockIdx.x;
  const int i0 = it * 256;
  const int h = blockIdx.y;
  const int b = blockIdx.z;
  const int t = threadIdx.x, lane = t & 63, wave = t >> 6;
  const int ql = lane & 15;
  const int kg = lane >> 4;
  const int q7 = ql & 7;
  const float LOG2E = 1.44269504089f;
  const float esf = edge_scale[0] * edge_w[h] * LOG2E;

  const int rs = 3 * DIM;  // 1536
  const bf16* qbase = qkv + (size_t)b * SEQ * rs + h * HD;
  const bf16* kbase = qbase + DIM;
  const bf16* vbase = qbase + 2 * DIM;

  bf16x8 qf[2][2];
#pragma unroll
  for (int mf = 0; mf < 2; mf++)
#pragma unroll
    for (int kf = 0; kf < 2; kf++) {
      bf16x8 q0 = *(const bf16x8*)(qbase + (size_t)(i0 + wave * 32 + mf * 16 + ql) * rs +
                                   kf * 32 + kg * 8);
#pragma unroll
      for (int e = 0; e < 8; e++) q0[e] = (bf16)((float)q0[e] * (0.125f * LOG2E));
      qf[mf][kf] = q0;
    }

  bf16x8 vones;
#pragma unroll
  for (int e = 0; e < 8; e++) vones[e] = (bf16)1.0f;

  const bf16* abase = Aperm + ((size_t)(b * 8 + it) * 16 * 8) * 4096 + (size_t)t * 8;

  float mreg[2] = {-1e30f, -1e30f};
  f32x4 lsum[2] = {};
  f32x4 oacc[2][4] = {};

  const int srow = t >> 2, sq4 = t & 3;
  const int jp = t & 63, doct = t >> 6;

  u32x4 rk0, rk1;
  us8 va0, va1;
  bf16x8 av[2][4];
  // ---- prologue: load tile0, write buf0, issue tile1, load av tile0 ----
  {
    const bf16* krow = kbase + (size_t)srow * rs + sq4 * 16;
    rk0 = *(const u32x4*)(krow);
    rk1 = *(const u32x4*)(krow + 8);
    const bf16* vr0 = vbase + (size_t)(2 * jp) * rs + doct * 8;
    va0 = *(const us8*)(vr0);
    va1 = *(const us8*)(vr0 + rs);
  }
  {
    *(u32x4*)&Kl[0][srow * 64 + (((2 * sq4 + 0) ^ (srow & 7)) << 3)] = rk0;
    *(u32x4*)&Kl[0][srow * 64 + (((2 * sq4 + 1) ^ (srow & 7)) << 3)] = rk1;
#pragma unroll
    for (int jj = 0; jj < 8; jj++) {
      unsigned w0 = (unsigned)va0[jj] | ((unsigned)va1[jj] << 16);
      *(unsigned*)&Vt[0][(doct * 8 + jj) * 128 + (((jp >> 2) ^ jj) << 3) + 2 * (jp & 3)] = w0;
    }
  }
  {
    const bf16* krow = kbase + (size_t)(128 + srow) * rs + sq4 * 16;
    rk0 = *(const u32x4*)(krow);
    rk1 = *(const u32x4*)(krow + 8);
    const bf16* vr0 = vbase + (size_t)(128 + 2 * jp) * rs + doct * 8;
    va0 = *(const us8*)(vr0);
    va1 = *(const us8*)(vr0 + rs);
#pragma unroll
    for (int mf = 0; mf < 2; mf++)
#pragma unroll
      for (int c = 0; c < 4; c++)
        av[mf][c] = *(const bf16x8*)(abase + (size_t)(mf * 4 + c) * 4096);
  }
  __syncthreads();  // buf0 visible to all waves

  for (int jtid = 0; jtid < SEQ / 128; jtid++) {
    const int cur = jtid & 1;

    // S^T accumulator init from current tile's bias (av = tile jtid)
    f32x4 st[2][8];
#pragma unroll
    for (int mf = 0; mf < 2; mf++)
#pragma unroll
      for (int c = 0; c < 4; c++)
#pragma unroll
        for (int r = 0; r < 4; r++) {
          st[mf][2 * c][r] = esf * (float)av[mf][c][r];
          st[mf][2 * c + 1][r] = esf * (float)av[mf][c][4 + r];
        }
    // issue av loads for tile jtid+1
    if (jtid + 1 < SEQ / 128) {
#pragma unroll
      for (int mf = 0; mf < 2; mf++)
#pragma unroll
        for (int c = 0; c < 4; c++)
          av[mf][c] = *(const bf16x8*)(abase + (size_t)((jtid + 1) * 8 + mf * 4 + c) * 4096);
    }

    // QK^T from Kl[cur]
    __builtin_amdgcn_s_setprio(1);
#pragma unroll
    for (int kf = 0; kf < 2; kf++)
#pragma unroll
      for (int nf = 0; nf < 8; nf++) {
        bf16x8 kfr =
            *(const bf16x8*)&Kl[cur][(nf * 16 + ql) * 64 + ((((kf << 2) + kg) ^ q7) << 3)];
        st[0][nf] = mfma16(kfr, qf[0][kf], st[0][nf]);
        st[1][nf] = mfma16(kfr, qf[1][kf], st[1][nf]);
      }
    __builtin_amdgcn_s_setprio(0);

    // write tile jtid+1 (regs) -> buf[cur^1]; its last readers finished at barrier jtid-1
    if (jtid + 1 < SEQ / 128) {
      *(u32x4*)&Kl[cur ^ 1][srow * 64 + (((2 * sq4 + 0) ^ (srow & 7)) << 3)] = rk0;
      *(u32x4*)&Kl[cur ^ 1][srow * 64 + (((2 * sq4 + 1) ^ (srow & 7)) << 3)] = rk1;
#pragma unroll
      for (int jj = 0; jj < 8; jj++) {
        unsigned w0 = (unsigned)va0[jj] | ((unsigned)va1[jj] << 16);
        *(unsigned*)&Vt[cur ^ 1][(doct * 8 + jj) * 128 + (((jp >> 2) ^ jj) << 3) + 2 * (jp & 3)] =
            w0;
      }
      // issue tile jtid+2 global loads
      if (jtid + 2 < SEQ / 128) {
        const int jn = (jtid + 2) * 128;
        const bf16* krow = kbase + (size_t)(jn + srow) * rs + sq4 * 16;
        rk0 = *(const u32x4*)(krow);
        rk1 = *(const u32x4*)(krow + 8);
        const bf16* vr0 = vbase + (size_t)(jn + 2 * jp) * rs + doct * 8;
        va0 = *(const us8*)(vr0);
        va1 = *(const us8*)(vr0 + rs);
      }
    }

    // online softmax per mf half, defer-max THR=8 (log2 domain)
#pragma unroll
    for (int mf = 0; mf < 2; mf++) {
      float rmax = st[mf][0][0];
#pragma unroll
      for (int nf = 0; nf < 8; nf++)
#pragma unroll
        for (int r = 0; r < 4; r++) rmax = fmaxf(rmax, st[mf][nf][r]);
      rmax = fmaxf(rmax, __shfl_xor(rmax, 16));
      rmax = fmaxf(rmax, __shfl_xor(rmax, 32));
      if (__any(rmax > mreg[mf] + 8.0f)) {
        float mnew = fmaxf(mreg[mf], rmax);
        float corr = exp2f(mreg[mf] - mnew);
        mreg[mf] = mnew;
#pragma unroll
        for (int r = 0; r < 4; r++) {
          float c = __shfl(corr, kg * 4 + r);
          lsum[mf][r] *= c;
#pragma unroll
          for (int nd = 0; nd < 4; nd++) oacc[mf][nd][r] *= c;
        }
      }
#pragma unroll
      for (int nf = 0; nf < 8; nf++) {
        bf16x4 pk;
#pragma unroll
        for (int r = 0; r < 4; r++) pk[r] = (bf16)exp2f(st[mf][nf][r] - mreg[mf]);
        *(bf16x4*)&Pl[wave][mf][ql * 128 + (((2 * nf + (kg >> 1)) ^ q7) << 3) + (kg & 1) * 4] = pk;
      }
    }

    // O += P V from Vt[cur]
    __builtin_amdgcn_s_setprio(1);
#pragma unroll
    for (int kf = 0; kf < 4; kf++) {
      bf16x8 pa0 = *(const bf16x8*)&Pl[wave][0][ql * 128 + ((((kf << 2) + kg) ^ q7) << 3)];
      bf16x8 pa1 = *(const bf16x8*)&Pl[wave][1][ql * 128 + ((((kf << 2) + kg) ^ q7) << 3)];
      lsum[0] = mfma16(pa0, vones, lsum[0]);
      lsum[1] = mfma16(pa1, vones, lsum[1]);
#pragma unroll
      for (int nd = 0; nd < 4; nd++) {
        bf16x8 vv =
            *(const bf16x8*)&Vt[cur][(nd * 16 + ql) * 128 + ((((kf << 2) + kg) ^ q7) << 3)];
        oacc[0][nd] = mfma16(pa0, vv, oacc[0][nd]);
        oacc[1][nd] = mfma16(pa1, vv, oacc[1][nd]);
      }
    }
    __builtin_amdgcn_s_setprio(0);

    __syncthreads();  // one barrier per tile
  }

#pragma unroll
  for (int mf = 0; mf < 2; mf++)
#pragma unroll
    for (int r = 0; r < 4; r++) {
      float rinv = 1.0f / lsum[mf][r];
      int irow = i0 + wave * 32 + mf * 16 + kg * 4 + r;
      bf16* orow = out + ((size_t)b * SEQ + irow) * DIM + h * HD;
#pragma unroll
      for (int nd = 0; nd < 4; nd++) orow[nd * 16 + ql] = (bf16)(oacc[mf][nd][r] * rinv);
    }
}

// ---------- workspace layout ----------
constexpr size_t OFF_WQKV = 0;                                    // 1536x512 bf16
constexpr size_t OFF_WPROJ = OFF_WQKV + (size_t)1536 * 512 * 2;   // 512x512 bf16
constexpr size_t OFF_W1 = OFF_WPROJ + (size_t)512 * 512 * 2;      // 2048x512 bf16
constexpr size_t OFF_W2 = OFF_W1 + (size_t)2048 * 512 * 2;        // 512x2048 bf16
constexpr size_t OFF_XW = OFF_W2 + (size_t)512 * 2048 * 2;        // 8192x512 bf16 (x / y1)
constexpr size_t OFF_SHARED = OFF_XW + (size_t)NROWS * DIM * 2;   // qkv (24MB) / ffn1 (32MB)
constexpr size_t OFF_ATTNOUT = OFF_SHARED + (size_t)NROWS * 2048 * 2;  // 8192x512 bf16
constexpr size_t OFF_APERM = OFF_ATTNOUT + (size_t)NROWS * DIM * 2;    // 4x2048x2048 bf16
constexpr size_t WS_NEED = OFF_APERM + (size_t)BATCH * SEQ * SEQ * 2;  // ~90 MB

extern "C" void kernel_launch(void* const* d_in, const int* in_sizes, int n_in,
                              void* d_out, int out_size, void* d_ws, size_t ws_size,
                              hipStream_t stream) {
  const float* H = (const float*)d_in[0];
  const float* A = (const float*)d_in[1];
  const float* ln1_g = (const float*)d_in[2];
  const float* ln1_b = (const float*)d_in[3];
  const float* qkv_w = (const float*)d_in[4];
  const float* qkv_b = (const float*)d_in[5];
  const float* proj_w = (const float*)d_in[6];
  const float* proj_b = (const float*)d_in[7];
  const float* ln2_g = (const float*)d_in[8];
  const float* ln2_b = (const float*)d_in[9];
  const float* w1 = (const float*)d_in[10];
  const float* b1 = (const float*)d_in[11];
  const float* w2 = (const float*)d_in[12];
  const float* b2 = (const float*)d_in[13];
  const float* edge_w = (const float*)d_in[14];
  const float* edge_scale = (const float*)d_in[15];
  float* out = (float*)d_out;
  char* ws = (char*)d_ws;

  bf16* wqkv = (bf16*)(ws + OFF_WQKV);
  bf16* wproj = (bf16*)(ws + OFF_WPROJ);
  bf16* w1t = (bf16*)(ws + OFF_W1);
  bf16* w2t = (bf16*)(ws + OFF_W2);
  bf16* xw = (bf16*)(ws + OFF_XW);
  bf16* qkvb = (bf16*)(ws + OFF_SHARED);
  bf16* ffn1 = (bf16*)(ws + OFF_SHARED);
  bf16* attnout = (bf16*)(ws + OFF_ATTNOUT);
  bf16* aperm = (bf16*)(ws + OFF_APERM);

  // A -> bf16 permuted fragment-order blob (8-wave geometry)
  permute_a<<<dim3(16, 8, 4), 512, 0, stream>>>(A, aperm);
  // all weights -> bf16 transposed (N,K), fused single launch
  convert_all<<<3072, 256, 0, stream>>>(qkv_w, proj_w, w1, w2, wqkv, wproj, w1t, w2t);

  // x = LN1(H)
  ln_kernel<<<NROWS / 4, 256, 0, stream>>>(H, ln1_g, ln1_b, xw);
  // qkv = x @ qkv_w + qkv_b   (128x128 tiles, 768 blocks)
  gemm_bt<EPI_BF16, 4, 4><<<dim3(1536 / 128, NROWS / 128), 256, 0, stream>>>(
      xw, wqkv, qkv_b, nullptr, qkvb, NROWS, 1536, 512);
  // attention (8 waves x 32 q-rows, dbuf K/V, 1 barrier/tile)
  attn_kernel<<<dim3(SEQ / 256, NHEAD, BATCH), 512, 0, stream>>>(qkvb, aperm, edge_w, edge_scale,
                                                                 attnout);
  // H2 = H + attnout @ proj_w + proj_b   (64x64 tiles -> 1024 blocks = 4/CU)
  gemm_bt<EPI_RESID, 2, 2><<<dim3(512 / 64, NROWS / 64), 256, 0, stream>>>(
      attnout, wproj, proj_b, H, out, NROWS, 512, 512);
  // y1 = LN2(H2)
  ln_kernel<<<NROWS / 4, 256, 0, stream>>>(out, ln2_g, ln2_b, xw);
  // ffn1 = gelu(y1 @ w1 + b1)   (128x128 tiles, 1024 blocks)
  gemm_bt<EPI_GELU, 4, 4><<<dim3(2048 / 128, NROWS / 128), 256, 0, stream>>>(
      xw, w1t, b1, nullptr, ffn1, NROWS, 2048, 512);
  // out = H2 + ffn1 @ w2 + b2   (64x64 tiles -> 1024 blocks = 4/CU)
  gemm_bt<EPI_RESID, 2, 2><<<dim3(512 / 64, NROWS / 64), 256, 0, stream>>>(
      ffn1, w2t, b2, out, out, NROWS, 512, 2048);
}